// Round 13
// baseline (79.034 us; speedup 1.0000x reference)
//
#include <hip/hip_runtime.h>
#include <cstdint>
#include <cstddef>

typedef _Float16 f16x8 __attribute__((ext_vector_type(8)));
typedef _Float16 f16x4 __attribute__((ext_vector_type(4)));
typedef float    f32x4 __attribute__((ext_vector_type(4)));

#define MFMA16(a,b,c) __builtin_amdgcn_mfma_f32_16x16x32_f16((a),(b),(c),0,0,0)

// ws layout (halfs) — weights in 16x16-MFMA fragment-linear order (R12-proven):
//   W1F  [15][4ot][8kk][64][8] @0       (245760)
//   W16F [4ot][12kk][64][8]    @245760  (24576)   sp=32kk+8(l>>4)+j; x col=1808+sp; zero sp<12 or sp>=368
//   W2F  [16t][8kk][64][8]     @270336  (65536)
//   W3F  [17t][8kk][64][8]     @335872  (69632)   o>=260 zero
__global__ void tea_prep(const float* __restrict__ W1, const float* __restrict__ W16,
                         const float* __restrict__ W2, const float* __restrict__ W3,
                         _Float16* __restrict__ ws)
{
    int i = blockIdx.x * blockDim.x + threadIdx.x;
    if (i < 245760) {
        int win = i >> 14, t = i & 16383;
        int ot = t >> 12, kk = (t >> 9) & 7, l = (t >> 3) & 63, j = t & 7;
        int o = 16 * ot + (l & 15);
        int s = 32 * kk + 8 * (l >> 4) + j;
        ws[i] = (_Float16)W1[(win * 256 + s) * 64 + o];
    } else if (i < 270336) {
        int t = i - 245760;
        int ot = t / 6144, t2 = t % 6144;
        int kk = t2 >> 9, l = (t2 >> 3) & 63, j = t2 & 7;
        int o = 16 * ot + (l & 15);
        int sp = 32 * kk + 8 * (l >> 4) + j;
        ws[i] = (_Float16)((sp >= 12 && sp < 368) ? W16[(sp - 12) * 64 + o] : 0.f);
    } else if (i < 335872) {
        int t = i - 270336;
        int q2 = t >> 12, kk = (t >> 9) & 7, l = (t >> 3) & 63, j = t & 7;
        int og = 16 * q2 + (l & 15);
        int g = q2 >> 2, o2 = og - 64 * g;
        int s = 32 * kk + 8 * (l >> 4) + j;
        ws[i] = (_Float16)W2[(g * 256 + s) * 64 + o2];
    } else if (i < 405504) {
        int t = i - 335872;
        int tt = t >> 12, kk = (t >> 9) & 7, l = (t >> 3) & 63, j = t & 7;
        int o = 16 * tt + (l & 15);
        int s = 32 * kk + 8 * (l >> 4) + j;
        ws[i] = (_Float16)((o < 260) ? W3[s * 260 + o] : 0.f);
    }
}

// DMA-pipelined fused kernel: 512 blocks x 32 rows, 1024 threads (16 waves), 1 block/CU.
// LDS sh[73984] halfs = 147968 B:
//   ring: 5 slots x [32 rows][512 B] fp32 chunks, halfs [0, 40960)
//         (source-XOR-swizzled: byte-in-row ^= (row&7)<<4, applied on DMA src AND reads)
//   y   : [32][1032] f16, halfs [40960, 73984)
//   z   : [32][264]  f16, halfs [0, 8448)    (alias ring; written after l1 done)
//   ps  : f32 [17][32][10], halfs [8448, 19328)  (alias ring; written after l3)
__global__ __launch_bounds__(1024, 4)
void tea_dma(const float* __restrict__ x,
             const float* __restrict__ b1,  const float* __restrict__ b16,
             const float* __restrict__ b2,  const float* __restrict__ b3,
             const _Float16* __restrict__ ws, float* __restrict__ out)
{
    __shared__ _Float16 sh[73984];
    char* shb = (char*)sh;

    const int tid = threadIdx.x;
    const int bid = blockIdx.x;
    const int wg  = (bid & 7) * 64 + (bid >> 3);      // bijective XCD swizzle (512%8==0)
    const int q = tid >> 6, l = tid & 63, r = l & 15, kg = l >> 4;

    const char* xb = (const char*)(x + (size_t)wg * 32 * 2176);

    // one global_load_lds per wave per chunk: wave q covers chunk rows 2q, 2q+1.
    auto issue = [&](int c) {
        int row = 2 * q + (l >> 5);
        int colphys = (l & 31) * 16;
        int collog = colphys ^ ((row & 7) << 4);      // inverse-swizzle the SOURCE
        const void* src = xb + (size_t)row * 8704 + (size_t)c * 512 + collog;
        void* dst = shb + (c % 5) * 16384 + q * 1024; // wave-uniform, linear
        __builtin_amdgcn_global_load_lds(
            (const __attribute__((address_space(1))) void*)src,
            (__attribute__((address_space(3))) void*)dst, 16, 0, 0);
    };

#define PASSTOP() do { \
    asm volatile("s_waitcnt lgkmcnt(0) vmcnt(0)" ::: "memory"); \
    __builtin_amdgcn_s_barrier(); \
    __builtin_amdgcn_sched_barrier(0); } while (0)

    // B-frag from ring: 8 fp32 at (row, fp32-col colgrp..+8) of chunk in slotbyte
    auto bfrag = [&](int slotbyte, int rowloc, int colb) -> f16x8 {
        int swz = (rowloc & 7) << 4;
        f32x4 u = *(const f32x4*)(shb + slotbyte + rowloc * 512 + (colb ^ swz));
        f32x4 v = *(const f32x4*)(shb + slotbyte + rowloc * 512 + ((colb + 16) ^ swz));
        f16x8 B;
        B[0] = (_Float16)u[0]; B[1] = (_Float16)u[1]; B[2] = (_Float16)u[2]; B[3] = (_Float16)u[3];
        B[4] = (_Float16)v[0]; B[5] = (_Float16)v[1]; B[6] = (_Float16)v[2]; B[7] = (_Float16)v[3];
        return B;
    };

    // window compute: this wave = (win, rh, ot=q&3); 16 rows x 16 outs, K=256
    auto wincomp = [&](int win, int rh, const float* bp, int ybase) {
        const _Float16* A = ws + win * 16384 + (q & 3) * 4096;
        const int rowloc = 16 * rh + r;
        f32x4 acc = {0.f, 0.f, 0.f, 0.f};
        #pragma unroll
        for (int kk = 0; kk < 8; ++kk) {
            int slotb = ((win + (kk >> 2)) % 5) * 16384;
            int colb = 128 * (kk & 3) + 32 * kg;
            f16x8 B  = bfrag(slotb, rowloc, colb);
            f16x8 Af = *(const f16x8*)(A + kk * 512 + l * 8);
            acc = MFMA16(Af, B, acc);
        }
        float4 bv = *(const float4*)(bp + 16 * (q & 3) + 4 * kg);
        f16x4 pk;
        pk[0] = (_Float16)fmaxf(acc[0] + bv.x, 0.f);
        pk[1] = (_Float16)fmaxf(acc[1] + bv.y, 0.f);
        pk[2] = (_Float16)fmaxf(acc[2] + bv.z, 0.f);
        pk[3] = (_Float16)fmaxf(acc[3] + bv.w, 0.f);
        *(f16x4*)&sh[40960 + rowloc * 1032 + ybase + 16 * (q & 3) + 4 * kg] = pk;
    };

    // y16 tail: K=368 at x col 1808 (chunk 14 byte-offset 64); clamped k only hits zero weights
    auto y16comp = [&](int rh) {
        const _Float16* A = ws + 245760 + (q & 3) * 6144;
        const int rowloc = 16 * rh + r;
        f32x4 acc = {0.f, 0.f, 0.f, 0.f};
        #pragma unroll
        for (int kk = 0; kk < 12; ++kk) {
            int off32 = 16 + 32 * kk + 8 * kg;        // fp32 offset from chunk-14 base
            if (32 * kk + 8 * kg >= 368) off32 = 376; // sp>=368 -> zero weights; any valid addr
            int cc = off32 >> 7;                      // 0,1,2 -> chunks 14,15,16 -> slots 4,0,1
            int slotb = ((cc == 0) ? 4 : (cc - 1)) * 16384;
            int colb = (off32 & 127) * 4;
            f16x8 B  = bfrag(slotb, rowloc, colb);
            f16x8 Af = *(const f16x8*)(A + kk * 512 + l * 8);
            acc = MFMA16(Af, B, acc);
        }
        float4 bv = *(const float4*)(b16 + 16 * (q & 3) + 4 * kg);
        f16x4 pk;
        pk[0] = (_Float16)fmaxf(acc[0] + bv.x, 0.f);
        pk[1] = (_Float16)fmaxf(acc[1] + bv.y, 0.f);
        pk[2] = (_Float16)fmaxf(acc[2] + bv.z, 0.f);
        pk[3] = (_Float16)fmaxf(acc[3] + bv.w, 0.f);
        *(f16x4*)&sh[40960 + rowloc * 1032 + 960 + 16 * (q & 3) + 4 * kg] = pk;
    };

    // ---- prologue: chunks 0,1,2 in flight ----
    issue(0); issue(1); issue(2);

    // ---- l1: 7 window-pair passes + (win14 | y16) pass ----
    #pragma unroll
    for (int p = 0; p < 7; ++p) {
        PASSTOP();                                   // chunks <= 2p+2 delivered, everywhere
        issue(2 * p + 3); issue(2 * p + 4);
        int win = 2 * p + (q >> 3);
        int rh  = (q >> 2) & 1;
        wincomp(win, rh, b1 + win * 64, 64 * win);
    }
    PASSTOP();                                       // chunks 14,15,16 delivered
    {
        int rh = (q >> 2) & 1;
        if (q < 8) wincomp(14, rh, b1 + 14 * 64, 64 * 14);
        else       y16comp(rh);
    }
    PASSTOP();                                       // y complete; ring dead

    // ---- layer 2: wave (rh2=q>>3, j=q&7) -> z tiles j, j+8 ----
    {
        const int rh2 = q >> 3, j = q & 7;
        #pragma unroll
        for (int s2 = 0; s2 < 2; ++s2) {
            int t = j + 8 * s2;
            const _Float16* A = ws + 270336 + t * 4096;
            f32x4 acc = {0.f, 0.f, 0.f, 0.f};
            #pragma unroll
            for (int kk = 0; kk < 8; ++kk) {
                f16x8 B  = *(const f16x8*)&sh[40960 + (16 * rh2 + r) * 1032 + (t >> 2) * 256 + 32 * kk + 8 * kg];
                f16x8 Af = *(const f16x8*)(A + kk * 512 + l * 8);
                acc = MFMA16(Af, B, acc);
            }
            float4 bv = *(const float4*)(b2 + 16 * t + 4 * kg);
            f16x4 pk;
            pk[0] = (_Float16)fmaxf(acc[0] + bv.x, 0.f);
            pk[1] = (_Float16)fmaxf(acc[1] + bv.y, 0.f);
            pk[2] = (_Float16)fmaxf(acc[2] + bv.z, 0.f);
            pk[3] = (_Float16)fmaxf(acc[3] + bv.w, 0.f);
            *(f16x4*)&sh[(16 * rh2 + r) * 264 + 16 * t + 4 * kg] = pk;
        }
    }
    PASSTOP();                                       // z published

    // ---- layer 3: jobs (t, rh) over 17 tiles x 2 halves; pool -> ps ----
    {
        float* psp = (float*)(sh + 8448);
        auto l3job = [&](int t, int rh2) {
            const _Float16* A = ws + 335872 + t * 4096;
            f32x4 acc = {0.f, 0.f, 0.f, 0.f};
            #pragma unroll
            for (int kk = 0; kk < 8; ++kk) {
                f16x8 B  = *(const f16x8*)&sh[(16 * rh2 + r) * 264 + 32 * kk + 8 * kg];
                f16x8 Af = *(const f16x8*)(A + kk * 512 + l * 8);
                acc = MFMA16(Af, B, acc);
            }
            float p[10];
            #pragma unroll
            for (int c = 0; c < 10; ++c) p[c] = 0.f;
            #pragma unroll
            for (int tt = 0; tt < 4; ++tt) {
                int o = 16 * t + 4 * kg + tt;
                if (o < 260) p[(unsigned)o / 26u] += fmaxf(acc[tt] + b3[o], 0.f);
            }
            #pragma unroll
            for (int c = 0; c < 10; ++c) {
                p[c] += __shfl_xor(p[c], 16);
                p[c] += __shfl_xor(p[c], 32);
            }
            if (kg == 0) {
                #pragma unroll
                for (int c = 0; c < 10; ++c)
                    psp[t * 320 + (16 * rh2 + r) * 10 + c] = p[c];
            }
        };
        l3job(q >> 1, q & 1);
        l3job((q + 16) >> 1, q & 1);
        if (q < 2) l3job(16, q);
    }
    PASSTOP();                                       // ps in

    // ---- final: threads 0..31 = rows; sum 17 tiles; softmax; out ----
    if (tid < 32) {
        const float* psp = (const float*)(sh + 8448);
        float v[10];
        #pragma unroll
        for (int c = 0; c < 10; ++c) {
            float s = 0.f;
            #pragma unroll
            for (int t = 0; t < 17; ++t) s += psp[t * 320 + tid * 10 + c];
            v[c] = s;
        }
        float mx = v[0];
        #pragma unroll
        for (int c = 1; c < 10; ++c) mx = fmaxf(mx, v[c]);
        float e[10], se = 0.f;
        #pragma unroll
        for (int c = 0; c < 10; ++c) { e[c] = expf(v[c] - mx); se += e[c]; }
        float inv = 1.f / se;
        float* orow = out + (size_t)(wg * 32 + tid) * 10;
        #pragma unroll
        for (int c = 0; c < 10; ++c) orow[c] = e[c] * inv;
    }
#undef PASSTOP
}

extern "C" void kernel_launch(void* const* d_in, const int* in_sizes, int n_in,
                              void* d_out, int out_size, void* d_ws, size_t ws_size,
                              hipStream_t stream)
{
    const float* x   = (const float*)d_in[0];
    const float* W1  = (const float*)d_in[1];
    const float* b1  = (const float*)d_in[2];
    const float* W16 = (const float*)d_in[3];
    const float* b16 = (const float*)d_in[4];
    const float* W2  = (const float*)d_in[5];
    const float* b2  = (const float*)d_in[6];
    const float* W3  = (const float*)d_in[7];
    const float* b3  = (const float*)d_in[8];
    float*    out = (float*)d_out;
    _Float16* ws  = (_Float16*)d_ws;

    tea_prep<<<1584, 256, 0, stream>>>(W1, W16, W2, W3, ws);
    tea_dma <<<512, 1024, 0, stream>>>(x, b1, b16, b2, b3, ws, out);
}